// Round 5
// baseline (119.994 us; speedup 1.0000x reference)
//
#include <hip/hip_runtime.h>
#include <math.h>

#define CCH 64
#define NVOX 4096
#define NB 2
#define RS 72   // padded LDS row stride in halves (64 data + 8 pad = 144 B)

typedef _Float16 f16x8 __attribute__((ext_vector_type(8)));
typedef _Float16 f16x4 __attribute__((ext_vector_type(4)));
typedef __fp16   g16x2 __attribute__((ext_vector_type(2)));  // cvt_pkrtz result type
typedef float f32x4 __attribute__((ext_vector_type(4)));

// ---------------- Kernel A: fused QKV projection ----------------
// x: [B, C, N] fp32; W*: [C, C] (out, in); b*: [C]
// qh, kh: [B, N, C] f16 ; vh: [B, C, N] f16
__global__ __launch_bounds__(256) void qkv_proj(
    const float* __restrict__ x,
    const float* __restrict__ Wq, const float* __restrict__ bq,
    const float* __restrict__ Wk, const float* __restrict__ bk,
    const float* __restrict__ Wv, const float* __restrict__ bv,
    _Float16* __restrict__ qh, _Float16* __restrict__ kh, _Float16* __restrict__ vh)
{
    __shared__ float Ws[3 * 64 * 64];   // 48 KB
    __shared__ float xs[64 * 32];       // 8 KB
    const int t  = threadIdx.x;
    const int b  = blockIdx.x >> 7;          // 128 tiles of 32 voxels per batch
    const int i0 = (blockIdx.x & 127) * 32;

    {
        const float4* Wq4 = (const float4*)Wq;
        const float4* Wk4 = (const float4*)Wk;
        const float4* Wv4 = (const float4*)Wv;
        float4* Ws4 = (float4*)Ws;
#pragma unroll
        for (int s = 0; s < 4; ++s) {
            int idx = t + 256 * s;
            Ws4[idx]        = Wq4[idx];
            Ws4[1024 + idx] = Wk4[idx];
            Ws4[2048 + idx] = Wv4[idx];
        }
    }
    {
        int cc = t >> 2;
        int m0 = (t & 3) * 8;
        const float* src = x + ((b * CCH + cc) * NVOX) + i0 + m0;
#pragma unroll
        for (int s = 0; s < 8; ++s) xs[cc * 32 + m0 + s] = src[s];
    }
    __syncthreads();

    const int vox = t & 31;
    const int c0  = (t >> 5) * 8;

#pragma unroll
    for (int m = 0; m < 3; ++m) {
        const float* Wm  = &Ws[m * 4096];
        const float* bia = (m == 0) ? bq : (m == 1) ? bk : bv;
        float acc[8];
#pragma unroll
        for (int j = 0; j < 8; ++j) acc[j] = bia[c0 + j];
        for (int cc = 0; cc < 64; cc += 4) {
            float xv0 = xs[(cc + 0) * 32 + vox];
            float xv1 = xs[(cc + 1) * 32 + vox];
            float xv2 = xs[(cc + 2) * 32 + vox];
            float xv3 = xs[(cc + 3) * 32 + vox];
#pragma unroll
            for (int j = 0; j < 8; ++j) {
                float4 w = *(const float4*)&Wm[(c0 + j) * 64 + cc];
                acc[j] = fmaf(w.x, xv0, acc[j]);
                acc[j] = fmaf(w.y, xv1, acc[j]);
                acc[j] = fmaf(w.z, xv2, acc[j]);
                acc[j] = fmaf(w.w, xv3, acc[j]);
            }
        }
        if (m < 2) {
            f16x8 hv;
#pragma unroll
            for (int j = 0; j < 8; ++j) hv[j] = (_Float16)acc[j];
            _Float16* dst = ((m == 0) ? qh : kh) + ((b * NVOX) + i0 + vox) * CCH + c0;
            *(f16x8*)dst = hv;
        } else {
#pragma unroll
            for (int j = 0; j < 8; ++j)
                vh[(b * CCH + c0 + j) * NVOX + i0 + vox] = (_Float16)acc[j];
        }
    }
}

// ---------------- Kernel B: MFMA flash attention (S^T, double-buffered) ----------------
template <int SPLIT>
__global__ __launch_bounds__(256) void attn(
    const _Float16* __restrict__ qh, const _Float16* __restrict__ kh,
    const _Float16* __restrict__ vh,
    _Float16* __restrict__ po,  // [B*SPLIT][64][N] unnormalized O^T partials (f16)
    float* __restrict__ ml,     // [B*SPLIT][N][2] (m, l)
    float* __restrict__ out)    // [B][C][N]
{
    __shared__ _Float16 ksl[2][64 * RS];   // [buf][j][c]
    __shared__ _Float16 vsl[2][64 * RS];   // [buf][c][j]

    constexpr int LS = (SPLIT == 8) ? 3 : (SPLIT == 4) ? 2 : (SPLIT == 2) ? 1 : 0;
    const int t    = threadIdx.x;
    const int h    = blockIdx.x & (SPLIT - 1);
    const int tile = blockIdx.x >> LS;
    const int b    = tile >> 6;
    const int i0   = (tile & 63) * 64;

    const int lane = t & 63;
    const int w    = t >> 6;         // wave id: rows [w*16, w*16+16)
    const int q4   = lane >> 4;      // quad id
    const int n    = lane & 15;      // this lane's row: i = i0 + w*16 + n

    const int row = t >> 2;          // staging row 0..63
    const int c0  = (t & 3) * 16;    // staging col offset (halves)
    const int JT  = 64 / SPLIT;

    auto load_tile = [&](int jt, float4 r[4]) {
        const int j0 = (h * JT + jt) * 64;
        const float4* ks = (const float4*)&kh[((size_t)(b * NVOX) + j0 + row) * CCH + c0];
        r[0] = ks[0]; r[1] = ks[1];
        const float4* vs = (const float4*)&vh[((size_t)b * CCH + row) * NVOX + j0 + c0];
        r[2] = vs[0]; r[3] = vs[1];
    };
    auto store_tile = [&](int buf, const float4 r[4]) {
        *(float4*)&ksl[buf][row * RS + c0]     = r[0];
        *(float4*)&ksl[buf][row * RS + c0 + 8] = r[1];
        *(float4*)&vsl[buf][row * RS + c0]     = r[2];
        *(float4*)&vsl[buf][row * RS + c0 + 8] = r[3];
    };

    // Q B-operand fragments, straight from global
    f16x8 aq[2];
    {
        const _Float16* qrow = qh + ((size_t)(b * NVOX) + i0 + w * 16 + n) * CCH + q4 * 8;
        aq[0] = *(const f16x8*)(qrow);
        aq[1] = *(const f16x8*)(qrow + 32);
    }

    float4 stg[4];
    load_tile(0, stg);
    store_tile(0, stg);

    float m_prev = -1e30f, l = 0.f;
    f32x4 o[4];
#pragma unroll
    for (int mt = 0; mt < 4; ++mt) o[mt] = (f32x4){0.f, 0.f, 0.f, 0.f};

    __syncthreads();

    for (int jt = 0; jt < JT; ++jt) {
        const int buf = jt & 1;
        if (jt + 1 < JT) load_tile(jt + 1, stg);   // in flight during compute

        // S^T = K Q^T : s[nt][r] = S[i][j = j0 + nt*16 + q4*4 + r]
        f32x4 s[4];
#pragma unroll
        for (int nt = 0; nt < 4; ++nt) s[nt] = (f32x4){0.f, 0.f, 0.f, 0.f};
#pragma unroll
        for (int ks = 0; ks < 2; ++ks) {
#pragma unroll
            for (int nt = 0; nt < 4; ++nt) {
                f16x8 ak = *(const f16x8*)&ksl[buf][(nt * 16 + n) * RS + ks * 32 + q4 * 8];
                s[nt] = __builtin_amdgcn_mfma_f32_16x16x32_f16(ak, aq[ks], s[nt], 0, 0, 0);
            }
        }

        // per-lane online softmax (all 16 values belong to row i = lane&15)
        float mx = -1e30f;
#pragma unroll
        for (int nt = 0; nt < 4; ++nt)
#pragma unroll
            for (int r = 0; r < 4; ++r) mx = fmaxf(mx, s[nt][r]);
        mx = fmaxf(mx, __shfl_xor(mx, 16, 64));
        mx = fmaxf(mx, __shfl_xor(mx, 32, 64));
        const float mn = fmaxf(m_prev, mx);

        float p[4][4], sum = 0.f;
#pragma unroll
        for (int nt = 0; nt < 4; ++nt)
#pragma unroll
            for (int r = 0; r < 4; ++r) {
                p[nt][r] = __expf(s[nt][r] - mn);
                sum += p[nt][r];
            }
        sum += __shfl_xor(sum, 16, 64);
        sum += __shfl_xor(sum, 32, 64);

        const float alpha = __expf(m_prev - mn);
        l = l * alpha + sum;
        m_prev = mn;

#pragma unroll
        for (int mt = 0; mt < 4; ++mt)
#pragma unroll
            for (int r = 0; r < 4; ++r) o[mt][r] *= alpha;

        // packed cvt: P^T B-fragments for K=16 MFMA, straight from registers
        f16x4 bp[4];
#pragma unroll
        for (int nt = 0; nt < 4; ++nt) {
            union { g16x2 g2[2]; f16x4 h4; } u;
            u.g2[0] = __builtin_amdgcn_cvt_pkrtz(p[nt][0], p[nt][1]);
            u.g2[1] = __builtin_amdgcn_cvt_pkrtz(p[nt][2], p[nt][3]);
            bp[nt] = u.h4;
        }

        // O^T += V^T P^T
#pragma unroll
        for (int nt = 0; nt < 4; ++nt) {
#pragma unroll
            for (int mt = 0; mt < 4; ++mt) {
                f16x4 av = *(const f16x4*)&vsl[buf][(mt * 16 + n) * RS + nt * 16 + q4 * 4];
                o[mt] = __builtin_amdgcn_mfma_f32_16x16x16f16(av, bp[nt], o[mt], 0, 0, 0);
            }
        }

        if (jt + 1 < JT) {
            __syncthreads();               // all waves done reading buf^1 (tile jt-1)
            store_tile(buf ^ 1, stg);
            __syncthreads();               // tile jt+1 visible
        }
    }

    const int ig = i0 + w * 16 + n;   // global i this lane holds (O^T col)
    if (SPLIT > 1) {
        const size_t base = ((size_t)(b * SPLIT + h) * 64) * NVOX;
#pragma unroll
        for (int mt = 0; mt < 4; ++mt)
#pragma unroll
            for (int r = 0; r < 4; ++r)
                po[base + (size_t)(mt * 16 + q4 * 4 + r) * NVOX + ig] = (_Float16)o[mt][r];
        if (q4 == 0) {
            float2* mlp = (float2*)&ml[((size_t)(b * SPLIT + h) * NVOX + ig) * 2];
            *mlp = make_float2(m_prev, l);
        }
    } else {
        const float inv = 1.0f / l;
#pragma unroll
        for (int mt = 0; mt < 4; ++mt)
#pragma unroll
            for (int r = 0; r < 4; ++r)
                out[(size_t)(b * CCH + mt * 16 + q4 * 4 + r) * NVOX + ig] = o[mt][r] * inv;
    }
}

// ---------------- Kernel C: combine split-j partials (f16 partials) ----------------
template <int SPLIT>
__global__ __launch_bounds__(256) void combine(
    const _Float16* __restrict__ po, const float* __restrict__ ml,
    float* __restrict__ out)
{
    __shared__ float wls[SPLIT * 64];
    const int t  = threadIdx.x;
    const int b  = blockIdx.x >> 6;
    const int i0 = (blockIdx.x & 63) * 64;

    if (t < 64) {
        const int i = i0 + t;
        float mv[SPLIT], lv[SPLIT], M = -1e30f;
#pragma unroll
        for (int h = 0; h < SPLIT; ++h) {
            mv[h] = ml[((size_t)(b * SPLIT + h) * NVOX + i) * 2 + 0];
            lv[h] = ml[((size_t)(b * SPLIT + h) * NVOX + i) * 2 + 1];
            M = fmaxf(M, mv[h]);
        }
        float den = 0.f;
#pragma unroll
        for (int h = 0; h < SPLIT; ++h) den += lv[h] * __expf(mv[h] - M);
        const float inv = 1.0f / den;
#pragma unroll
        for (int h = 0; h < SPLIT; ++h) wls[h * 64 + t] = __expf(mv[h] - M) * inv;
    }
    __syncthreads();

    const int c  = t >> 2;
    const int iq = t & 3;
    float acc[16];
#pragma unroll
    for (int u = 0; u < 16; ++u) acc[u] = 0.f;
#pragma unroll
    for (int h = 0; h < SPLIT; ++h) {
        const f16x8* src = (const f16x8*)&po[((size_t)(b * SPLIT + h) * 64 + c) * NVOX + i0 + iq * 16];
        const float* wp  = &wls[h * 64 + iq * 16];
#pragma unroll
        for (int u = 0; u < 2; ++u) {
            f16x8 f = src[u];
#pragma unroll
            for (int e = 0; e < 8; ++e)
                acc[u * 8 + e] = fmaf((float)f[e], wp[u * 8 + e], acc[u * 8 + e]);
        }
    }
    float4* dst = (float4*)&out[(size_t)(b * CCH + c) * NVOX + i0 + iq * 16];
#pragma unroll
    for (int u = 0; u < 4; ++u)
        dst[u] = make_float4(acc[u * 4], acc[u * 4 + 1], acc[u * 4 + 2], acc[u * 4 + 3]);
}

extern "C" void kernel_launch(void* const* d_in, const int* in_sizes, int n_in,
                              void* d_out, int out_size, void* d_ws, size_t ws_size,
                              hipStream_t stream)
{
    const float* x  = (const float*)d_in[0];
    const float* Wq = (const float*)d_in[1];
    const float* bq = (const float*)d_in[2];
    const float* Wk = (const float*)d_in[3];
    const float* bk = (const float*)d_in[4];
    const float* Wv = (const float*)d_in[5];
    const float* bv = (const float*)d_in[6];
    float* out = (float*)d_out;

    _Float16* qh = (_Float16*)d_ws;                 // B*N*C halves
    _Float16* kh = qh + NB * NVOX * CCH;
    _Float16* vh = kh + NB * NVOX * CCH;
    _Float16* po = vh + NB * NVOX * CCH;            // B*SPLIT*64*N halves
    const size_t qkv_bytes = (size_t)3 * NB * NVOX * CCH * sizeof(_Float16);

    qkv_proj<<<NB * (NVOX / 32), 256, 0, stream>>>(x, Wq, bq, Wk, bk, Wv, bv, qh, kh, vh);

    const size_t need8 = qkv_bytes +
        (size_t)NB * 8 * 64 * NVOX * sizeof(_Float16) + (size_t)NB * 8 * NVOX * 2 * sizeof(float);
    const size_t need4 = qkv_bytes +
        (size_t)NB * 4 * 64 * NVOX * sizeof(_Float16) + (size_t)NB * 4 * NVOX * 2 * sizeof(float);
    const size_t need2 = qkv_bytes +
        (size_t)NB * 2 * 64 * NVOX * sizeof(_Float16) + (size_t)NB * 2 * NVOX * 2 * sizeof(float);

    if (ws_size >= need8) {
        float* ml = (float*)(po + (size_t)NB * 8 * 64 * NVOX);
        attn<8><<<NB * 64 * 8, 256, 0, stream>>>(qh, kh, vh, po, ml, out);
        combine<8><<<NB * 64, 256, 0, stream>>>(po, ml, out);
    } else if (ws_size >= need4) {
        float* ml = (float*)(po + (size_t)NB * 4 * 64 * NVOX);
        attn<4><<<NB * 64 * 4, 256, 0, stream>>>(qh, kh, vh, po, ml, out);
        combine<4><<<NB * 64, 256, 0, stream>>>(po, ml, out);
    } else if (ws_size >= need2) {
        float* ml = (float*)(po + (size_t)NB * 2 * 64 * NVOX);
        attn<2><<<NB * 64 * 2, 256, 0, stream>>>(qh, kh, vh, po, ml, out);
        combine<2><<<NB * 64, 256, 0, stream>>>(po, ml, out);
    } else {
        attn<1><<<NB * 64, 256, 0, stream>>>(qh, kh, vh, nullptr, nullptr, out);
    }
}

// Round 6
// 109.100 us; speedup vs baseline: 1.0999x; 1.0999x over previous
//
#include <hip/hip_runtime.h>
#include <math.h>

#define CCH 64
#define NVOX 4096
#define NB 2
#define RS 72    // padded LDS row stride in halves (64 data + 8 pad = 144 B)
#define TS 136   // epilogue transpose row stride in halves (128 data + 8 pad)

typedef _Float16 f16x8 __attribute__((ext_vector_type(8)));
typedef _Float16 f16x4 __attribute__((ext_vector_type(4)));
typedef __fp16   g16x2 __attribute__((ext_vector_type(2)));  // cvt_pkrtz result type
typedef float f32x4 __attribute__((ext_vector_type(4)));

// ---------------- Kernel A: fused QKV projection ----------------
// x: [B, C, N] fp32; W*: [C, C] (out, in); b*: [C]
// qh, kh: [B, N, C] f16 ; vh: [B, C, N] f16
__global__ __launch_bounds__(256) void qkv_proj(
    const float* __restrict__ x,
    const float* __restrict__ Wq, const float* __restrict__ bq,
    const float* __restrict__ Wk, const float* __restrict__ bk,
    const float* __restrict__ Wv, const float* __restrict__ bv,
    _Float16* __restrict__ qh, _Float16* __restrict__ kh, _Float16* __restrict__ vh)
{
    __shared__ float Ws[3 * 64 * 64];   // 48 KB
    __shared__ float xs[64 * 32];       // 8 KB
    const int t  = threadIdx.x;
    const int b  = blockIdx.x >> 7;          // 128 tiles of 32 voxels per batch
    const int i0 = (blockIdx.x & 127) * 32;

    {
        const float4* Wq4 = (const float4*)Wq;
        const float4* Wk4 = (const float4*)Wk;
        const float4* Wv4 = (const float4*)Wv;
        float4* Ws4 = (float4*)Ws;
#pragma unroll
        for (int s = 0; s < 4; ++s) {
            int idx = t + 256 * s;
            Ws4[idx]        = Wq4[idx];
            Ws4[1024 + idx] = Wk4[idx];
            Ws4[2048 + idx] = Wv4[idx];
        }
    }
    {
        int cc = t >> 2;
        int m0 = (t & 3) * 8;
        const float* src = x + ((b * CCH + cc) * NVOX) + i0 + m0;
#pragma unroll
        for (int s = 0; s < 8; ++s) xs[cc * 32 + m0 + s] = src[s];
    }
    __syncthreads();

    const int vox = t & 31;
    const int c0  = (t >> 5) * 8;

#pragma unroll
    for (int m = 0; m < 3; ++m) {
        const float* Wm  = &Ws[m * 4096];
        const float* bia = (m == 0) ? bq : (m == 1) ? bk : bv;
        float acc[8];
#pragma unroll
        for (int j = 0; j < 8; ++j) acc[j] = bia[c0 + j];
        for (int cc = 0; cc < 64; cc += 4) {
            float xv0 = xs[(cc + 0) * 32 + vox];
            float xv1 = xs[(cc + 1) * 32 + vox];
            float xv2 = xs[(cc + 2) * 32 + vox];
            float xv3 = xs[(cc + 3) * 32 + vox];
#pragma unroll
            for (int j = 0; j < 8; ++j) {
                float4 w = *(const float4*)&Wm[(c0 + j) * 64 + cc];
                acc[j] = fmaf(w.x, xv0, acc[j]);
                acc[j] = fmaf(w.y, xv1, acc[j]);
                acc[j] = fmaf(w.z, xv2, acc[j]);
                acc[j] = fmaf(w.w, xv3, acc[j]);
            }
        }
        if (m < 2) {
            f16x8 hv;
#pragma unroll
            for (int j = 0; j < 8; ++j) hv[j] = (_Float16)acc[j];
            _Float16* dst = ((m == 0) ? qh : kh) + ((b * NVOX) + i0 + vox) * CCH + c0;
            *(f16x8*)dst = hv;
        } else {
#pragma unroll
            for (int j = 0; j < 8; ++j)
                vh[(b * CCH + c0 + j) * NVOX + i0 + vox] = (_Float16)acc[j];
        }
    }
}

// ---------------- Kernel B: MFMA flash attention ----------------
// Block: 128-row i-tile (4 waves x 32 rows), 1/SPLIT of j range, double-buffered.
// Each wave owns 2 groups of 16 rows; K/V LDS reads are shared across both.
template <int SPLIT>
__global__ __launch_bounds__(256) void attn(
    const _Float16* __restrict__ qh, const _Float16* __restrict__ kh,
    const _Float16* __restrict__ vh,
    _Float16* __restrict__ po,  // [B*SPLIT][64][N] unnormalized O^T partials (f16)
    float* __restrict__ ml,     // [B*SPLIT][N][2] (m, l)
    float* __restrict__ out)    // [B][C][N]
{
    __shared__ _Float16 ksl[2][64 * RS];   // [buf][j][c]  (reused for epilogue transpose)
    __shared__ _Float16 vsl[2][64 * RS];   // [buf][c][j]

    constexpr int LS = (SPLIT == 8) ? 3 : (SPLIT == 4) ? 2 : (SPLIT == 2) ? 1 : 0;
    const int t    = threadIdx.x;
    const int h    = blockIdx.x & (SPLIT - 1);
    const int tile = blockIdx.x >> LS;
    const int b    = tile >> 5;          // 32 tiles of 128 rows per batch
    const int i0   = (tile & 31) * 128;

    const int lane = t & 63;
    const int w    = t >> 6;         // wave id: rows [w*32, w*32+32)
    const int q4   = lane >> 4;      // quad id
    const int n    = lane & 15;      // row within group: i = i0 + w*32 + g*16 + n

    const int row = t >> 2;          // staging row 0..63
    const int c0  = (t & 3) * 16;    // staging col offset (halves)
    const int JT  = 64 / SPLIT;

    auto load_tile = [&](int jt, float4 r[4]) {
        const int j0 = (h * JT + jt) * 64;
        const float4* ks = (const float4*)&kh[((size_t)(b * NVOX) + j0 + row) * CCH + c0];
        r[0] = ks[0]; r[1] = ks[1];
        const float4* vs = (const float4*)&vh[((size_t)b * CCH + row) * NVOX + j0 + c0];
        r[2] = vs[0]; r[3] = vs[1];
    };
    auto store_tile = [&](int buf, const float4 r[4]) {
        *(float4*)&ksl[buf][row * RS + c0]     = r[0];
        *(float4*)&ksl[buf][row * RS + c0 + 8] = r[1];
        *(float4*)&vsl[buf][row * RS + c0]     = r[2];
        *(float4*)&vsl[buf][row * RS + c0 + 8] = r[3];
    };

    // Q B-operand fragments for both 16-row groups, straight from global
    f16x8 aq[2][2];
#pragma unroll
    for (int g = 0; g < 2; ++g) {
        const _Float16* qrow =
            qh + ((size_t)(b * NVOX) + i0 + w * 32 + g * 16 + n) * CCH + q4 * 8;
        aq[g][0] = *(const f16x8*)(qrow);
        aq[g][1] = *(const f16x8*)(qrow + 32);
    }

    float4 stg[4];
    load_tile(0, stg);
    store_tile(0, stg);

    float m_prev[2] = {-1e30f, -1e30f}, l[2] = {0.f, 0.f};
    f32x4 o[2][4];
#pragma unroll
    for (int g = 0; g < 2; ++g)
#pragma unroll
        for (int mt = 0; mt < 4; ++mt) o[g][mt] = (f32x4){0.f, 0.f, 0.f, 0.f};

    __syncthreads();

    for (int jt = 0; jt < JT; ++jt) {
        const int buf = jt & 1;
        if (jt + 1 < JT) load_tile(jt + 1, stg);   // in flight during compute

        // S^T = K Q^T for both groups; K fragments read once, used twice
        f32x4 s[2][4];
#pragma unroll
        for (int g = 0; g < 2; ++g)
#pragma unroll
            for (int nt = 0; nt < 4; ++nt) s[g][nt] = (f32x4){0.f, 0.f, 0.f, 0.f};
#pragma unroll
        for (int ks = 0; ks < 2; ++ks) {
#pragma unroll
            for (int nt = 0; nt < 4; ++nt) {
                f16x8 ak = *(const f16x8*)&ksl[buf][(nt * 16 + n) * RS + ks * 32 + q4 * 8];
                s[0][nt] = __builtin_amdgcn_mfma_f32_16x16x32_f16(ak, aq[0][ks], s[0][nt], 0, 0, 0);
                s[1][nt] = __builtin_amdgcn_mfma_f32_16x16x32_f16(ak, aq[1][ks], s[1][nt], 0, 0, 0);
            }
        }

        // per-lane online softmax for both groups
        f16x4 bp[2][4];
        float alpha[2];
#pragma unroll
        for (int g = 0; g < 2; ++g) {
            float mx = -1e30f;
#pragma unroll
            for (int nt = 0; nt < 4; ++nt)
#pragma unroll
                for (int r = 0; r < 4; ++r) mx = fmaxf(mx, s[g][nt][r]);
            mx = fmaxf(mx, __shfl_xor(mx, 16, 64));
            mx = fmaxf(mx, __shfl_xor(mx, 32, 64));
            const float mn = fmaxf(m_prev[g], mx);

            float p[4][4], sum = 0.f;
#pragma unroll
            for (int nt = 0; nt < 4; ++nt)
#pragma unroll
                for (int r = 0; r < 4; ++r) {
                    p[nt][r] = __expf(s[g][nt][r] - mn);
                    sum += p[nt][r];
                }
            sum += __shfl_xor(sum, 16, 64);
            sum += __shfl_xor(sum, 32, 64);

            alpha[g]  = __expf(m_prev[g] - mn);
            l[g]      = l[g] * alpha[g] + sum;
            m_prev[g] = mn;

#pragma unroll
            for (int nt = 0; nt < 4; ++nt) {
                union { g16x2 g2[2]; f16x4 h4; } u;
                u.g2[0] = __builtin_amdgcn_cvt_pkrtz(p[nt][0], p[nt][1]);
                u.g2[1] = __builtin_amdgcn_cvt_pkrtz(p[nt][2], p[nt][3]);
                bp[g][nt] = u.h4;
            }
        }

#pragma unroll
        for (int g = 0; g < 2; ++g)
#pragma unroll
            for (int mt = 0; mt < 4; ++mt)
#pragma unroll
                for (int r = 0; r < 4; ++r) o[g][mt][r] *= alpha[g];

        // O^T += V^T P^T ; V fragments read once, used for both groups
#pragma unroll
        for (int nt = 0; nt < 4; ++nt) {
#pragma unroll
            for (int mt = 0; mt < 4; ++mt) {
                f16x4 av = *(const f16x4*)&vsl[buf][(mt * 16 + n) * RS + nt * 16 + q4 * 4];
                o[0][mt] = __builtin_amdgcn_mfma_f32_16x16x16f16(av, bp[0][nt], o[0][mt], 0, 0, 0);
                o[1][mt] = __builtin_amdgcn_mfma_f32_16x16x16f16(av, bp[1][nt], o[1][mt], 0, 0, 0);
            }
        }

        if (jt + 1 < JT) {
            __syncthreads();               // all waves done reading buf^1 (tile jt-1)
            store_tile(buf ^ 1, stg);
            __syncthreads();               // tile jt+1 visible
        }
    }

    if (SPLIT > 1) {
        // epilogue: transpose O^T through LDS (reuse ksl) for coalesced f16 stores
        __syncthreads();                       // everyone done with ksl/vsl
        _Float16* tb = &ksl[0][0];             // 64 x TS halves = 17408 B (fits 18432)
#pragma unroll
        for (int g = 0; g < 2; ++g)
#pragma unroll
            for (int mt = 0; mt < 4; ++mt)
#pragma unroll
                for (int r = 0; r < 4; ++r)
                    tb[(mt * 16 + q4 * 4 + r) * TS + w * 32 + g * 16 + n] =
                        (_Float16)o[g][mt][r];
#pragma unroll
        for (int g = 0; g < 2; ++g) {
            if (q4 == 0) {
                const int ig = i0 + w * 32 + g * 16 + n;
                float2* mlp = (float2*)&ml[((size_t)(b * SPLIT + h) * NVOX + ig) * 2];
                *mlp = make_float2(m_prev[g], l[g]);
            }
        }
        __syncthreads();
        const int cr = t >> 2;                 // 0..63 output row
        const int ib = (t & 3) * 32;           // i-chunk base within 128
        const size_t base = ((size_t)(b * SPLIT + h) * 64 + cr) * NVOX + i0 + ib;
#pragma unroll
        for (int u = 0; u < 4; ++u) {
            f16x8 vv = *(const f16x8*)&tb[cr * TS + ib + u * 8];
            *(f16x8*)&po[base + u * 8] = vv;
        }
    } else {
#pragma unroll
        for (int g = 0; g < 2; ++g) {
            const int ig = i0 + w * 32 + g * 16 + n;
            const float inv = 1.0f / l[g];
#pragma unroll
            for (int mt = 0; mt < 4; ++mt)
#pragma unroll
                for (int r = 0; r < 4; ++r)
                    out[(size_t)(b * CCH + mt * 16 + q4 * 4 + r) * NVOX + ig] =
                        o[g][mt][r] * inv;
        }
    }
}

// ---------------- Kernel C: combine split-j partials (f16 partials) ----------------
template <int SPLIT>
__global__ __launch_bounds__(256) void combine(
    const _Float16* __restrict__ po, const float* __restrict__ ml,
    float* __restrict__ out)
{
    __shared__ float wls[SPLIT * 64];
    const int t  = threadIdx.x;
    const int b  = blockIdx.x >> 6;
    const int i0 = (blockIdx.x & 63) * 64;

    if (t < 64) {
        const int i = i0 + t;
        float mv[SPLIT], lv[SPLIT], M = -1e30f;
#pragma unroll
        for (int h = 0; h < SPLIT; ++h) {
            mv[h] = ml[((size_t)(b * SPLIT + h) * NVOX + i) * 2 + 0];
            lv[h] = ml[((size_t)(b * SPLIT + h) * NVOX + i) * 2 + 1];
            M = fmaxf(M, mv[h]);
        }
        float den = 0.f;
#pragma unroll
        for (int h = 0; h < SPLIT; ++h) den += lv[h] * __expf(mv[h] - M);
        const float inv = 1.0f / den;
#pragma unroll
        for (int h = 0; h < SPLIT; ++h) wls[h * 64 + t] = __expf(mv[h] - M) * inv;
    }
    __syncthreads();

    const int c  = t >> 2;
    const int iq = t & 3;
    float acc[16];
#pragma unroll
    for (int u = 0; u < 16; ++u) acc[u] = 0.f;
#pragma unroll
    for (int h = 0; h < SPLIT; ++h) {
        const f16x8* src = (const f16x8*)&po[((size_t)(b * SPLIT + h) * 64 + c) * NVOX + i0 + iq * 16];
        const float* wp  = &wls[h * 64 + iq * 16];
#pragma unroll
        for (int u = 0; u < 2; ++u) {
            f16x8 f = src[u];
#pragma unroll
            for (int e = 0; e < 8; ++e)
                acc[u * 8 + e] = fmaf((float)f[e], wp[u * 8 + e], acc[u * 8 + e]);
        }
    }
    float4* dst = (float4*)&out[(size_t)(b * CCH + c) * NVOX + i0 + iq * 16];
#pragma unroll
    for (int u = 0; u < 4; ++u)
        dst[u] = make_float4(acc[u * 4], acc[u * 4 + 1], acc[u * 4 + 2], acc[u * 4 + 3]);
}

extern "C" void kernel_launch(void* const* d_in, const int* in_sizes, int n_in,
                              void* d_out, int out_size, void* d_ws, size_t ws_size,
                              hipStream_t stream)
{
    const float* x  = (const float*)d_in[0];
    const float* Wq = (const float*)d_in[1];
    const float* bq = (const float*)d_in[2];
    const float* Wk = (const float*)d_in[3];
    const float* bk = (const float*)d_in[4];
    const float* Wv = (const float*)d_in[5];
    const float* bv = (const float*)d_in[6];
    float* out = (float*)d_out;

    _Float16* qh = (_Float16*)d_ws;                 // B*N*C halves
    _Float16* kh = qh + NB * NVOX * CCH;
    _Float16* vh = kh + NB * NVOX * CCH;
    _Float16* po = vh + NB * NVOX * CCH;            // B*SPLIT*64*N halves
    const size_t qkv_bytes = (size_t)3 * NB * NVOX * CCH * sizeof(_Float16);

    qkv_proj<<<NB * (NVOX / 32), 256, 0, stream>>>(x, Wq, bq, Wk, bk, Wv, bv, qh, kh, vh);

    const size_t need8 = qkv_bytes +
        (size_t)NB * 8 * 64 * NVOX * sizeof(_Float16) + (size_t)NB * 8 * NVOX * 2 * sizeof(float);
    const size_t need4 = qkv_bytes +
        (size_t)NB * 4 * 64 * NVOX * sizeof(_Float16) + (size_t)NB * 4 * NVOX * 2 * sizeof(float);
    const size_t need2 = qkv_bytes +
        (size_t)NB * 2 * 64 * NVOX * sizeof(_Float16) + (size_t)NB * 2 * NVOX * 2 * sizeof(float);

    if (ws_size >= need8) {
        float* ml = (float*)(po + (size_t)NB * 8 * 64 * NVOX);
        attn<8><<<NB * 32 * 8, 256, 0, stream>>>(qh, kh, vh, po, ml, out);
        combine<8><<<NB * 64, 256, 0, stream>>>(po, ml, out);
    } else if (ws_size >= need4) {
        float* ml = (float*)(po + (size_t)NB * 4 * 64 * NVOX);
        attn<4><<<NB * 32 * 4, 256, 0, stream>>>(qh, kh, vh, po, ml, out);
        combine<4><<<NB * 64, 256, 0, stream>>>(po, ml, out);
    } else if (ws_size >= need2) {
        float* ml = (float*)(po + (size_t)NB * 2 * 64 * NVOX);
        attn<2><<<NB * 32 * 2, 256, 0, stream>>>(qh, kh, vh, po, ml, out);
        combine<2><<<NB * 64, 256, 0, stream>>>(po, ml, out);
    } else {
        attn<1><<<NB * 32, 256, 0, stream>>>(qh, kh, vh, nullptr, nullptr, out);
    }
}